// Round 1
// baseline (349.113 us; speedup 1.0000x reference)
//
#include <hip/hip_runtime.h>
#include <math.h>

#define HH 1024
#define WW 1024
#define NB 8
#define ROWS 32                       // rows per wave
#define STRIPES (WW / 64)             // 16
#define CHUNKS (HH / ROWS)            // 32
#define WAVES_PER_B (STRIPES * CHUNKS) // 512

// Accumulator layout in ws (floats): tp0, fn0, fp0, tp1, fn1, fp1
__global__ __launch_bounds__(256) void ul_main(const float* __restrict__ pred,
                                               const float* __restrict__ target,
                                               float* __restrict__ ws) {
    const int wid  = (blockIdx.x << 2) | (threadIdx.x >> 6);
    const int lane = threadIdx.x & 63;

    const int b      = wid / WAVES_PER_B;
    const int rem    = wid - b * WAVES_PER_B;
    const int stripe = rem & (STRIPES - 1);
    const int chunk  = rem / STRIPES;
    const int c0     = stripe * 64;
    const int r0     = chunk * ROWS;
    const int c      = c0 + lane;

    const float* __restrict__ t1p = target + (size_t)(2 * b + 1) * (HH * WW);
    const float* __restrict__ p0p = pred   + (size_t)(2 * b)     * (HH * WW);
    const float* __restrict__ p1p = p0p + (size_t)HH * WW;

    // extra-column address: lane 0 loads the left halo column, lane 1 the right
    const int excL = (c0 > 0) ? (c0 - 1) : 0;
    const int excR = (c0 + 64 < WW) ? (c0 + 64) : (WW - 1);
    const int exc  = (lane == 0) ? excL : excR;

    unsigned long long Bp, Ep, Bc, Ec, Bn, En;

    auto loadrow = [&](int h, unsigned long long& Bo, unsigned long long& Eo) {
        float v = t1p[(size_t)h * WW + c];
        Bo = __ballot(v > 0.5f);
        float ev = 0.0f;
        if (lane < 2) ev = t1p[(size_t)h * WW + exc];
        Eo = __ballot(ev > 0.5f);   // bit0 = left extra, bit1 = right extra
    };

    loadrow((r0 > 0) ? (r0 - 1) : 0, Bp, Ep);
    loadrow(r0, Bc, Ec);

    float a0 = 0.f, a1 = 0.f, a2 = 0.f, a3 = 0.f, a4 = 0.f, a5 = 0.f;

    for (int h = r0; h < r0 + ROWS; ++h) {
        const int hn = (h + 1 < HH) ? (h + 1) : (HH - 1);
        loadrow(hn, Bn, En);

        const unsigned long long aB = Bp & Bc & Bn;
        const unsigned long long oB = Bp | Bc | Bn;
        const unsigned long long aE = Ep & Ec & En;
        const unsigned long long oE = Ep | Ec | En;

        // 66-bit windows packed into 128-bit: bit (i+1) = column c0-1+i+1
        __uint128_t WA = (((__uint128_t)aB) << 1) | (unsigned long long)(aE & 1ull) |
                         (((__uint128_t)((aE >> 1) & 1ull)) << 65);
        __uint128_t WO = (((__uint128_t)oB) << 1) | (unsigned long long)(oE & 1ull) |
                         (((__uint128_t)((oE >> 1) & 1ull)) << 65);

        const unsigned wa = ((unsigned)(WA >> lane)) & 7u;
        const unsigned wo = ((unsigned)(WO >> lane)) & 7u;
        const bool uniform = (wa == 7u) || (wo == 0u);

        if (uniform) {
            const bool L = (Bc >> lane) & 1ull;
            const float t1v = L ? 0.95f : 0.05f;   // bit-exact vs reference smoothing
            const float t0v = L ? 0.05f : 0.95f;
            const size_t off = (size_t)h * WW + c;
            float x0 = p0p[off];
            float x1 = p1p[off];
            float p0 = 1.0f / (1.0f + expf(-x0));
            float p1 = 1.0f / (1.0f + expf(-x1));
            p0 = fminf(fmaxf(p0, 1e-7f), 1.0f - 1e-7f);
            p1 = fminf(fmaxf(p1, 1e-7f), 1.0f - 1e-7f);
            a0 += t0v * p0;
            a1 += t0v * (1.0f - p0);
            a2 += (1.0f - t0v) * p0;
            a3 += t1v * p1;
            a4 += t1v * (1.0f - p1);
            a5 += (1.0f - t1v) * p1;
        }

        Bp = Bc; Ep = Ec; Bc = Bn; Ec = En;
    }

    // wave reduction (64 lanes)
    #pragma unroll
    for (int off = 32; off; off >>= 1) {
        a0 += __shfl_xor(a0, off, 64);
        a1 += __shfl_xor(a1, off, 64);
        a2 += __shfl_xor(a2, off, 64);
        a3 += __shfl_xor(a3, off, 64);
        a4 += __shfl_xor(a4, off, 64);
        a5 += __shfl_xor(a5, off, 64);
    }
    if (lane == 0) {
        atomicAdd(&ws[0], a0);
        atomicAdd(&ws[1], a1);
        atomicAdd(&ws[2], a2);
        atomicAdd(&ws[3], a3);
        atomicAdd(&ws[4], a4);
        atomicAdd(&ws[5], a5);
    }
}

__global__ void ul_final(const float* __restrict__ ws, float* __restrict__ out) {
    const float tp0 = ws[0], fn0 = ws[1], fp0 = ws[2];
    const float tp1 = ws[3], fn1 = ws[4], fp1 = ws[5];
    const float d0 = (tp0 + 1e-7f) / (tp0 + 0.6f * fn0 + 0.4f * fp0 + 1e-7f);
    const float d1 = (tp1 + 1e-7f) / (tp1 + 0.6f * fn1 + 0.4f * fp1 + 1e-7f);
    const float back = 1.0f - d0;
    const float fore = sqrtf(fmaxf(1.0f - d1, 0.0f));  // (1-d)*(1-d)^-0.5
    out[0] = 0.5f * (back + fore);                     // WEIGHT=1 kills the CE term
}

extern "C" void kernel_launch(void* const* d_in, const int* in_sizes, int n_in,
                              void* d_out, int out_size, void* d_ws, size_t ws_size,
                              hipStream_t stream) {
    const float* pred   = (const float*)d_in[0];
    const float* target = (const float*)d_in[1];
    float* ws  = (float*)d_ws;
    float* out = (float*)d_out;

    hipMemsetAsync(d_ws, 0, 6 * sizeof(float), stream);

    const int total_waves = NB * WAVES_PER_B;   // 4096
    const int blocks = total_waves / 4;         // 1024 blocks of 4 waves
    ul_main<<<blocks, 256, 0, stream>>>(pred, target, ws);
    ul_final<<<1, 1, 0, stream>>>(ws, out);
}

// Round 2
// 31.760 us; speedup vs baseline: 10.9923x; 10.9923x over previous
//
#include <hip/hip_runtime.h>
#include <math.h>

#define HH 1024
#define WW 1024
#define NB 8
#define ROWS 16                         // rows per wave
#define STRIPES (WW / 64)               // 16
#define CHUNKS (HH / ROWS)              // 64
#define WAVES_PER_B (STRIPES * CHUNKS)  // 1024
#define TOTAL_WAVES (NB * WAVES_PER_B)  // 8192
#define NBLOCKS (TOTAL_WAVES / 4)       // 2048 blocks of 4 waves

// Stage 1: per-block partial sums (tp0,fn0,fp0,tp1,fn1,fp1) -> ws[block*6..]
__global__ __launch_bounds__(256) void ul_main(const float* __restrict__ pred,
                                               const float* __restrict__ target,
                                               float* __restrict__ partials) {
    const int wid  = (blockIdx.x << 2) | (threadIdx.x >> 6);
    const int lane = threadIdx.x & 63;

    const int b      = wid >> 10;          // / WAVES_PER_B (1024)
    const int rem    = wid & 1023;
    const int stripe = rem & (STRIPES - 1);
    const int chunk  = rem >> 4;           // / STRIPES (16)
    const int c0     = stripe * 64;
    const int r0     = chunk * ROWS;
    const int c      = c0 + lane;

    const float* __restrict__ t1p = target + (size_t)(2 * b + 1) * (HH * WW);
    const float* __restrict__ p0p = pred   + (size_t)(2 * b)     * (HH * WW);
    const float* __restrict__ p1p = p0p + (size_t)HH * WW;

    const int excL = (c0 > 0) ? (c0 - 1) : 0;
    const int excR = (c0 + 64 < WW) ? (c0 + 64) : (WW - 1);
    const int exc  = (lane == 0) ? excL : excR;

    // ---- phase 1: issue ALL label row loads (independent, pipelined) ----
    float vm[ROWS + 2], vx[ROWS + 2];
    #pragma unroll
    for (int i = 0; i < ROWS + 2; ++i) {
        int h = r0 - 1 + i;
        h = h < 0 ? 0 : (h >= HH ? HH - 1 : h);
        const size_t ro = (size_t)h * WW;
        vm[i] = t1p[ro + c];
        vx[i] = (lane < 2) ? t1p[ro + exc] : 0.0f;
    }

    // ---- phase 2: ballots (wave-uniform 64-bit row bitmaps) ----
    unsigned long long Bs[ROWS + 2], Es[ROWS + 2];
    #pragma unroll
    for (int i = 0; i < ROWS + 2; ++i) {
        Bs[i] = __ballot(vm[i] > 0.5f);
        Es[i] = __ballot(vx[i] > 0.5f);   // bit0 = left halo col, bit1 = right halo col
    }

    // ---- phase 3: 3x3 uniformity mask per row via bit ops ----
    unsigned uniM = 0, LM = 0;
    #pragma unroll
    for (int j = 0; j < ROWS; ++j) {
        const unsigned long long aB = Bs[j] & Bs[j + 1] & Bs[j + 2];
        const unsigned long long oB = Bs[j] | Bs[j + 1] | Bs[j + 2];
        const unsigned long long aE = Es[j] & Es[j + 1] & Es[j + 2];
        const unsigned long long oE = Es[j] | Es[j + 1] | Es[j + 2];
        __uint128_t WA = (((__uint128_t)aB) << 1) | (unsigned long long)(aE & 1ull) |
                         (((__uint128_t)((aE >> 1) & 1ull)) << 65);
        __uint128_t WO = (((__uint128_t)oB) << 1) | (unsigned long long)(oE & 1ull) |
                         (((__uint128_t)((oE >> 1) & 1ull)) << 65);
        const unsigned wa = ((unsigned)(WA >> lane)) & 7u;
        const unsigned wo = ((unsigned)(WO >> lane)) & 7u;
        const bool uni = (wa == 7u) || (wo == 0u);
        uniM |= (unsigned)uni << j;
        LM   |= (unsigned)((Bs[j + 1] >> lane) & 1ull) << j;
    }

    // ---- phase 4: issue ALL masked pred loads together ----
    float x0[ROWS], x1[ROWS];
    #pragma unroll
    for (int j = 0; j < ROWS; ++j) {
        if ((uniM >> j) & 1u) {
            const size_t off = (size_t)(r0 + j) * WW + c;
            x0[j] = p0p[off];
            x1[j] = p1p[off];
        }
    }

    // ---- phase 5: consume ----
    float a0 = 0.f, a1 = 0.f, a2 = 0.f, a3 = 0.f, a4 = 0.f, a5 = 0.f;
    #pragma unroll
    for (int j = 0; j < ROWS; ++j) {
        if ((uniM >> j) & 1u) {
            const bool L = (LM >> j) & 1u;
            const float t1v = L ? 0.95f : 0.05f;   // bit-exact smoothing values
            const float t0v = L ? 0.05f : 0.95f;
            float p0 = 1.0f / (1.0f + expf(-x0[j]));
            float p1 = 1.0f / (1.0f + expf(-x1[j]));
            p0 = fminf(fmaxf(p0, 1e-7f), 1.0f - 1e-7f);
            p1 = fminf(fmaxf(p1, 1e-7f), 1.0f - 1e-7f);
            a0 += t0v * p0;
            a1 += t0v * (1.0f - p0);
            a2 += (1.0f - t0v) * p0;
            a3 += t1v * p1;
            a4 += t1v * (1.0f - p1);
            a5 += (1.0f - t1v) * p1;
        }
    }

    // ---- wave reduce ----
    #pragma unroll
    for (int off = 32; off; off >>= 1) {
        a0 += __shfl_xor(a0, off, 64);
        a1 += __shfl_xor(a1, off, 64);
        a2 += __shfl_xor(a2, off, 64);
        a3 += __shfl_xor(a3, off, 64);
        a4 += __shfl_xor(a4, off, 64);
        a5 += __shfl_xor(a5, off, 64);
    }

    // ---- block reduce via LDS, then ONE plain store of 6 floats ----
    __shared__ float sm[4][6];
    const int wv = threadIdx.x >> 6;
    if (lane == 0) {
        sm[wv][0] = a0; sm[wv][1] = a1; sm[wv][2] = a2;
        sm[wv][3] = a3; sm[wv][4] = a4; sm[wv][5] = a5;
    }
    __syncthreads();
    if (threadIdx.x < 6) {
        const int k = threadIdx.x;
        partials[(size_t)blockIdx.x * 6 + k] = sm[0][k] + sm[1][k] + sm[2][k] + sm[3][k];
    }
}

// Stage 2: reduce 2048 partial vectors, compute the scalar loss
__global__ __launch_bounds__(256) void ul_final(const float* __restrict__ partials,
                                                float* __restrict__ out) {
    const int lane = threadIdx.x & 63;
    float s[6] = {0.f, 0.f, 0.f, 0.f, 0.f, 0.f};
    for (int i = threadIdx.x; i < NBLOCKS; i += 256) {
        #pragma unroll
        for (int k = 0; k < 6; ++k) s[k] += partials[(size_t)i * 6 + k];
    }
    #pragma unroll
    for (int off = 32; off; off >>= 1) {
        #pragma unroll
        for (int k = 0; k < 6; ++k) s[k] += __shfl_xor(s[k], off, 64);
    }
    __shared__ float sm[4][6];
    if (lane == 0) {
        const int wv = threadIdx.x >> 6;
        #pragma unroll
        for (int k = 0; k < 6; ++k) sm[wv][k] = s[k];
    }
    __syncthreads();
    if (threadIdx.x == 0) {
        float t[6];
        #pragma unroll
        for (int k = 0; k < 6; ++k) t[k] = sm[0][k] + sm[1][k] + sm[2][k] + sm[3][k];
        const float d0 = (t[0] + 1e-7f) / (t[0] + 0.6f * t[1] + 0.4f * t[2] + 1e-7f);
        const float d1 = (t[3] + 1e-7f) / (t[3] + 0.6f * t[4] + 0.4f * t[5] + 1e-7f);
        const float back = 1.0f - d0;
        const float fore = sqrtf(fmaxf(1.0f - d1, 0.0f));  // (1-d)*(1-d)^-0.5
        out[0] = 0.5f * (back + fore);                      // WEIGHT=1 kills CE term
    }
}

extern "C" void kernel_launch(void* const* d_in, const int* in_sizes, int n_in,
                              void* d_out, int out_size, void* d_ws, size_t ws_size,
                              hipStream_t stream) {
    const float* pred   = (const float*)d_in[0];
    const float* target = (const float*)d_in[1];
    float* partials = (float*)d_ws;   // 2048 * 6 floats = 48 KiB
    float* out      = (float*)d_out;

    ul_main<<<NBLOCKS, 256, 0, stream>>>(pred, target, partials);
    ul_final<<<1, 256, 0, stream>>>(partials, out);
}

// Round 3
// 26.856 us; speedup vs baseline: 12.9994x; 1.1826x over previous
//
#include <hip/hip_runtime.h>
#include <math.h>

#define HH 1024
#define WW 1024
#define NB 8
#define ROWS 16                      // output rows per wave
#define SW 256                       // stripe width (64 lanes * float4)
#define STRIPES (WW / SW)            // 4
#define CHUNKS (HH / ROWS)           // 64
#define WPB (STRIPES * CHUNKS)       // 256 waves per batch
#define TOTAL_WAVES (NB * WPB)       // 2048
#define NBLK (TOTAL_WAVES / 4)       // 512 blocks of 4 waves

// partials layout: ws[bid*8 + k], k = {Sp0, SLp0, Sp1, SLp1, N, NL, 0, 0}
__global__ __launch_bounds__(256) void ul_main(const float* __restrict__ pred,
                                               const float* __restrict__ target,
                                               float* __restrict__ partials) {
    const int wv   = threadIdx.x >> 6;
    const int lane = threadIdx.x & 63;
    const int wid  = (blockIdx.x << 2) | wv;
    const int b      = wid >> 8;         // 256 waves per batch
    const int rem    = wid & 255;
    const int stripe = rem & 3;
    const int chunk  = rem >> 2;
    const int c0     = stripe * SW;
    const int r0     = chunk * ROWS;
    const int col4   = c0 + lane * 4;

    const float* __restrict__ t1p = target + (size_t)(2 * b + 1) * (HH * WW);
    const float* __restrict__ p0p = pred   + (size_t)(2 * b)     * (HH * WW);
    const float* __restrict__ p1p = p0p + (size_t)HH * WW;

    const int excL = (c0 > 0) ? (c0 - 1) : 0;
    const int excR = (c0 + SW < WW) ? (c0 + SW) : (WW - 1);
    const int exc  = (lane == 0) ? excL : excR;

    // ---- phase 1: all label loads (independent float4 per row + halo scalar) ----
    float4 vm[ROWS + 2];
    unsigned ebPack = 0;                 // per-row halo bits (lane0=left col, lane1=right col)
    #pragma unroll
    for (int i = 0; i < ROWS + 2; ++i) {
        int h = r0 - 1 + i;
        h = h < 0 ? 0 : (h >= HH ? HH - 1 : h);
        const float* rp = t1p + (size_t)h * WW;
        vm[i] = *(const float4*)(rp + col4);
        float ev = (lane < 2) ? rp[exc] : 0.0f;
        ebPack |= (ev > 0.5f ? 1u : 0u) << i;
    }
    const unsigned ebR = __shfl(ebPack, 1);   // lane1's halo bits, for lane 63

    // ---- phase 2: pack 4 bits/row, build 6-bit windows (cols 4i-1 .. 4i+4) ----
    unsigned pbits[ROWS + 2], w6[ROWS + 2];
    #pragma unroll
    for (int i = 0; i < ROWS + 2; ++i) {
        unsigned p = (vm[i].x > 0.5f ? 1u : 0u) | (vm[i].y > 0.5f ? 2u : 0u) |
                     (vm[i].z > 0.5f ? 4u : 0u) | (vm[i].w > 0.5f ? 8u : 0u);
        pbits[i] = p;
        const unsigned pl = __shfl_up(p, 1);
        const unsigned pr = __shfl_down(p, 1);
        const unsigned lb = (lane == 0)  ? ((ebPack >> i) & 1u) : ((pl >> 3) & 1u);
        const unsigned rb = (lane == 63) ? ((ebR    >> i) & 1u) : (pr & 1u);
        w6[i] = lb | (p << 1) | (rb << 5);
    }

    // ---- phase 3: per-row uniformity mask + rare masked accumulation ----
    float s_p0 = 0.f, s_lp0 = 0.f, s_p1 = 0.f, s_lp1 = 0.f;
    int nC = 0, nL = 0;

    #pragma unroll
    for (int j = 0; j < ROWS; ++j) {
        const unsigned A = w6[j] & w6[j + 1] & w6[j + 2];
        const unsigned O = w6[j] | w6[j + 1] | w6[j + 2];
        const unsigned all1 = A & (A >> 1) & (A >> 2);
        const unsigned any1 = O | (O >> 1) | (O >> 2);
        const unsigned uni  = (all1 | ~any1) & 0xFu;
        if (uni) {
            const size_t off = (size_t)(r0 + j) * WW + col4;
            const float4 x0 = *(const float4*)(p0p + off);
            const float4 x1 = *(const float4*)(p1p + off);
            const unsigned lb4 = pbits[j + 1];
            nC += __popc(uni);
            nL += __popc(uni & lb4);
            #define UL_DO_K(K, C0, C1)                                          \
                if ((uni >> K) & 1u) {                                          \
                    float sg0 = 1.0f / (1.0f + expf(-(C0)));                    \
                    float sg1 = 1.0f / (1.0f + expf(-(C1)));                    \
                    sg0 = fminf(fmaxf(sg0, 1e-7f), 1.0f - 1e-7f);               \
                    sg1 = fminf(fmaxf(sg1, 1e-7f), 1.0f - 1e-7f);               \
                    s_p0 += sg0; s_p1 += sg1;                                   \
                    if ((lb4 >> K) & 1u) { s_lp0 += sg0; s_lp1 += sg1; }        \
                }
            UL_DO_K(0, x0.x, x1.x)
            UL_DO_K(1, x0.y, x1.y)
            UL_DO_K(2, x0.z, x1.z)
            UL_DO_K(3, x0.w, x1.w)
            #undef UL_DO_K
        }
    }

    // ---- wave reduce (4 floats + 2 ints) ----
    #pragma unroll
    for (int off = 32; off; off >>= 1) {
        s_p0  += __shfl_xor(s_p0,  off, 64);
        s_lp0 += __shfl_xor(s_lp0, off, 64);
        s_p1  += __shfl_xor(s_p1,  off, 64);
        s_lp1 += __shfl_xor(s_lp1, off, 64);
        nC    += __shfl_xor(nC,    off, 64);
        nL    += __shfl_xor(nL,    off, 64);
    }

    __shared__ float sm[4][6];
    if (lane == 0) {
        sm[wv][0] = s_p0;  sm[wv][1] = s_lp0;
        sm[wv][2] = s_p1;  sm[wv][3] = s_lp1;
        sm[wv][4] = (float)nC; sm[wv][5] = (float)nL;
    }
    __syncthreads();
    if (threadIdx.x < 8) {
        const int k = threadIdx.x;
        const float v = (k < 6) ? (sm[0][k] + sm[1][k] + sm[2][k] + sm[3][k]) : 0.0f;
        partials[(size_t)blockIdx.x * 8 + k] = v;
    }
}

// Stage 2: reduce 512 x 8 partials (float4, parity classes), compute scalar loss
__global__ __launch_bounds__(256) void ul_final(const float* __restrict__ ws,
                                                float* __restrict__ out) {
    const int t = threadIdx.x, lane = t & 63, wv = t >> 6;
    float a0 = 0.f, a1 = 0.f, a2 = 0.f, a3 = 0.f;
    #pragma unroll
    for (int r = 0; r < 4; ++r) {                 // 1024 float4s total
        const float4 v = ((const float4*)ws)[t + 256 * r];
        a0 += v.x; a1 += v.y; a2 += v.z; a3 += v.w;
    }
    // butterfly keeping parity class (even t = {Sp0,SLp0,Sp1,SLp1}, odd t = {N,NL,0,0})
    #pragma unroll
    for (int off = 32; off >= 2; off >>= 1) {
        a0 += __shfl_xor(a0, off, 64); a1 += __shfl_xor(a1, off, 64);
        a2 += __shfl_xor(a2, off, 64); a3 += __shfl_xor(a3, off, 64);
    }
    __shared__ float sm[4][2][4];
    if (lane < 2) {
        sm[wv][lane][0] = a0; sm[wv][lane][1] = a1;
        sm[wv][lane][2] = a2; sm[wv][lane][3] = a3;
    }
    __syncthreads();
    if (t == 0) {
        float Sp0 = 0.f, SLp0 = 0.f, Sp1 = 0.f, SLp1 = 0.f, N = 0.f, NL = 0.f;
        #pragma unroll
        for (int w = 0; w < 4; ++w) {
            Sp0 += sm[w][0][0]; SLp0 += sm[w][0][1];
            Sp1 += sm[w][0][2]; SLp1 += sm[w][0][3];
            N   += sm[w][1][0]; NL   += sm[w][1][1];
        }
        const float tp0 = 0.95f * Sp0 - 0.9f * SLp0;
        const float st0 = 0.95f * N   - 0.9f * NL;
        const float fn0 = st0 - tp0;
        const float fp0 = Sp0 - tp0;
        const float tp1 = 0.05f * Sp1 + 0.9f * SLp1;
        const float st1 = 0.05f * N   + 0.9f * NL;
        const float fn1 = st1 - tp1;
        const float fp1 = Sp1 - tp1;
        const float d0 = (tp0 + 1e-7f) / (tp0 + 0.6f * fn0 + 0.4f * fp0 + 1e-7f);
        const float d1 = (tp1 + 1e-7f) / (tp1 + 0.6f * fn1 + 0.4f * fp1 + 1e-7f);
        const float back = 1.0f - d0;
        const float fore = sqrtf(fmaxf(1.0f - d1, 0.0f));   // (1-d)*(1-d)^-0.5
        out[0] = 0.5f * (back + fore);                       // WEIGHT=1 kills CE term
    }
}

extern "C" void kernel_launch(void* const* d_in, const int* in_sizes, int n_in,
                              void* d_out, int out_size, void* d_ws, size_t ws_size,
                              hipStream_t stream) {
    const float* pred   = (const float*)d_in[0];
    const float* target = (const float*)d_in[1];
    float* partials = (float*)d_ws;    // 512 * 8 floats = 16 KiB
    float* out      = (float*)d_out;

    ul_main<<<NBLK, 256, 0, stream>>>(pred, target, partials);
    ul_final<<<1, 256, 0, stream>>>(partials, out);
}

// Round 4
// 21.618 us; speedup vs baseline: 16.1488x; 1.2423x over previous
//
#include <hip/hip_runtime.h>
#include <math.h>

#define HH 1024
#define WW 1024
#define NB 8
#define ROWS 8                       // output rows per wave
#define SW 256                       // stripe width (64 lanes * float4)
#define STRIPES (WW / SW)            // 4
#define CHUNKS (HH / ROWS)           // 128
#define WPB (STRIPES * CHUNKS)       // 512 waves per batch
#define TOTAL_WAVES (NB * WPB)       // 4096
#define NBLK (TOTAL_WAVES / 4)       // 1024 blocks of 4 waves

// partials layout: ws[bid*8 + k], k = {Sp0, SLp0, Sp1, SLp1, N, NL, 0, 0}
__global__ __launch_bounds__(256) void ul_main(const float* __restrict__ pred,
                                               const float* __restrict__ target,
                                               float* __restrict__ partials) {
    const int wv   = threadIdx.x >> 6;
    const int lane = threadIdx.x & 63;
    const int wid  = (blockIdx.x << 2) | wv;
    const int b      = wid >> 9;         // 512 waves per batch
    const int rem    = wid & 511;
    const int stripe = rem & 3;
    const int chunk  = rem >> 2;
    const int c0     = stripe * SW;
    const int r0     = chunk * ROWS;
    const int col4   = c0 + lane * 4;

    const float* __restrict__ t1p = target + (size_t)(2 * b + 1) * (HH * WW);
    const float* __restrict__ p0p = pred   + (size_t)(2 * b)     * (HH * WW);
    const float* __restrict__ p1p = p0p + (size_t)HH * WW;

    const int excL = (c0 > 0) ? (c0 - 1) : 0;
    const int excR = (c0 + SW < WW) ? (c0 + SW) : (WW - 1);
    const int exc  = (lane == 0) ? excL : excR;

    // ---- phase 1: ALL label loads (independent float4 per row + halo scalar) ----
    float4 vm[ROWS + 2];
    unsigned ebPack = 0;                 // per-row halo bits (lane0=left col, lane1=right col)
    #pragma unroll
    for (int i = 0; i < ROWS + 2; ++i) {
        int h = r0 - 1 + i;
        h = h < 0 ? 0 : (h >= HH ? HH - 1 : h);
        const float* rp = t1p + (size_t)h * WW;
        vm[i] = *(const float4*)(rp + col4);
        float ev = (lane < 2) ? rp[exc] : 0.0f;
        ebPack |= (ev > 0.5f ? 1u : 0u) << i;
    }
    const unsigned ebR = __shfl(ebPack, 1);   // lane1's halo bits, for lane 63

    // ---- phase 2: pack 4 bits/row, build 6-bit windows (cols 4i-1 .. 4i+4) ----
    unsigned pbits[ROWS + 2], w6[ROWS + 2];
    #pragma unroll
    for (int i = 0; i < ROWS + 2; ++i) {
        unsigned p = (vm[i].x > 0.5f ? 1u : 0u) | (vm[i].y > 0.5f ? 2u : 0u) |
                     (vm[i].z > 0.5f ? 4u : 0u) | (vm[i].w > 0.5f ? 8u : 0u);
        pbits[i] = p;
        const unsigned pl = __shfl_up(p, 1);
        const unsigned pr = __shfl_down(p, 1);
        const unsigned lb = (lane == 0)  ? ((ebPack >> i) & 1u) : ((pl >> 3) & 1u);
        const unsigned rb = (lane == 63) ? ((ebR    >> i) & 1u) : (pr & 1u);
        w6[i] = lb | (p << 1) | (rb << 5);
    }

    // ---- phase 3a: per-row 3x3 uniformity masks (pure ALU) ----
    unsigned unis[ROWS];
    #pragma unroll
    for (int j = 0; j < ROWS; ++j) {
        const unsigned A = w6[j] & w6[j + 1] & w6[j + 2];
        const unsigned O = w6[j] | w6[j + 1] | w6[j + 2];
        const unsigned all1 = A & (A >> 1) & (A >> 2);
        const unsigned any1 = O | (O >> 1) | (O >> 2);
        unis[j] = (all1 | ~any1) & 0xFu;
    }

    // ---- phase 3b: gather — branch bodies contain ONLY loads, so every
    // row's pred loads go in flight together (one vmcnt drain at first use) ----
    float4 x0[ROWS], x1[ROWS];
    #pragma unroll
    for (int j = 0; j < ROWS; ++j) {
        if (unis[j]) {
            const size_t off = (size_t)(r0 + j) * WW + col4;
            x0[j] = *(const float4*)(p0p + off);
            x1[j] = *(const float4*)(p1p + off);
        }
    }

    // ---- phase 3c: consume ----
    float s_p0 = 0.f, s_lp0 = 0.f, s_p1 = 0.f, s_lp1 = 0.f;
    int nC = 0, nL = 0;
    #pragma unroll
    for (int j = 0; j < ROWS; ++j) {
        const unsigned uni = unis[j];
        if (uni) {
            const unsigned lb4 = pbits[j + 1];
            nC += __popc(uni);
            nL += __popc(uni & lb4);
            #define UL_DO_K(K, C0, C1)                                          \
                if ((uni >> K) & 1u) {                                          \
                    float sg0 = 1.0f / (1.0f + expf(-(C0)));                    \
                    float sg1 = 1.0f / (1.0f + expf(-(C1)));                    \
                    sg0 = fminf(fmaxf(sg0, 1e-7f), 1.0f - 1e-7f);               \
                    sg1 = fminf(fmaxf(sg1, 1e-7f), 1.0f - 1e-7f);               \
                    s_p0 += sg0; s_p1 += sg1;                                   \
                    if ((lb4 >> K) & 1u) { s_lp0 += sg0; s_lp1 += sg1; }        \
                }
            UL_DO_K(0, x0[j].x, x1[j].x)
            UL_DO_K(1, x0[j].y, x1[j].y)
            UL_DO_K(2, x0[j].z, x1[j].z)
            UL_DO_K(3, x0[j].w, x1[j].w)
            #undef UL_DO_K
        }
    }

    // ---- wave reduce (4 floats + 2 ints) ----
    #pragma unroll
    for (int off = 32; off; off >>= 1) {
        s_p0  += __shfl_xor(s_p0,  off, 64);
        s_lp0 += __shfl_xor(s_lp0, off, 64);
        s_p1  += __shfl_xor(s_p1,  off, 64);
        s_lp1 += __shfl_xor(s_lp1, off, 64);
        nC    += __shfl_xor(nC,    off, 64);
        nL    += __shfl_xor(nL,    off, 64);
    }

    __shared__ float sm[4][6];
    if (lane == 0) {
        sm[wv][0] = s_p0;  sm[wv][1] = s_lp0;
        sm[wv][2] = s_p1;  sm[wv][3] = s_lp1;
        sm[wv][4] = (float)nC; sm[wv][5] = (float)nL;
    }
    __syncthreads();
    if (threadIdx.x < 8) {
        const int k = threadIdx.x;
        const float v = (k < 6) ? (sm[0][k] + sm[1][k] + sm[2][k] + sm[3][k]) : 0.0f;
        partials[(size_t)blockIdx.x * 8 + k] = v;
    }
}

// Stage 2: reduce 1024 x 8 partials (float4, parity classes), compute scalar loss
__global__ __launch_bounds__(256) void ul_final(const float* __restrict__ ws,
                                                float* __restrict__ out) {
    const int t = threadIdx.x, lane = t & 63, wv = t >> 6;
    float a0 = 0.f, a1 = 0.f, a2 = 0.f, a3 = 0.f;
    #pragma unroll
    for (int r = 0; r < 8; ++r) {                 // 2048 float4s total
        const float4 v = ((const float4*)ws)[t + 256 * r];
        a0 += v.x; a1 += v.y; a2 += v.z; a3 += v.w;
    }
    // butterfly keeping parity class (even t = {Sp0,SLp0,Sp1,SLp1}, odd t = {N,NL,0,0})
    #pragma unroll
    for (int off = 32; off >= 2; off >>= 1) {
        a0 += __shfl_xor(a0, off, 64); a1 += __shfl_xor(a1, off, 64);
        a2 += __shfl_xor(a2, off, 64); a3 += __shfl_xor(a3, off, 64);
    }
    __shared__ float sm[4][2][4];
    if (lane < 2) {
        sm[wv][lane][0] = a0; sm[wv][lane][1] = a1;
        sm[wv][lane][2] = a2; sm[wv][lane][3] = a3;
    }
    __syncthreads();
    if (t == 0) {
        float Sp0 = 0.f, SLp0 = 0.f, Sp1 = 0.f, SLp1 = 0.f, N = 0.f, NL = 0.f;
        #pragma unroll
        for (int w = 0; w < 4; ++w) {
            Sp0 += sm[w][0][0]; SLp0 += sm[w][0][1];
            Sp1 += sm[w][0][2]; SLp1 += sm[w][0][3];
            N   += sm[w][1][0]; NL   += sm[w][1][1];
        }
        const float tp0 = 0.95f * Sp0 - 0.9f * SLp0;
        const float st0 = 0.95f * N   - 0.9f * NL;
        const float fn0 = st0 - tp0;
        const float fp0 = Sp0 - tp0;
        const float tp1 = 0.05f * Sp1 + 0.9f * SLp1;
        const float st1 = 0.05f * N   + 0.9f * NL;
        const float fn1 = st1 - tp1;
        const float fp1 = Sp1 - tp1;
        const float d0 = (tp0 + 1e-7f) / (tp0 + 0.6f * fn0 + 0.4f * fp0 + 1e-7f);
        const float d1 = (tp1 + 1e-7f) / (tp1 + 0.6f * fn1 + 0.4f * fp1 + 1e-7f);
        const float back = 1.0f - d0;
        const float fore = sqrtf(fmaxf(1.0f - d1, 0.0f));   // (1-d)*(1-d)^-0.5
        out[0] = 0.5f * (back + fore);                       // WEIGHT=1 kills CE term
    }
}

extern "C" void kernel_launch(void* const* d_in, const int* in_sizes, int n_in,
                              void* d_out, int out_size, void* d_ws, size_t ws_size,
                              hipStream_t stream) {
    const float* pred   = (const float*)d_in[0];
    const float* target = (const float*)d_in[1];
    float* partials = (float*)d_ws;    // 1024 * 8 floats = 32 KiB
    float* out      = (float*)d_out;

    ul_main<<<NBLK, 256, 0, stream>>>(pred, target, partials);
    ul_final<<<1, 256, 0, stream>>>(partials, out);
}

// Round 5
// 20.912 us; speedup vs baseline: 16.6941x; 1.0338x over previous
//
#include <hip/hip_runtime.h>
#include <math.h>

#define HH 1024
#define WW 1024
#define NB 8
#define ROWS 8                       // output rows per block (full 1024-wide band)
#define CHUNKS (HH / ROWS)           // 128
#define NBLK (NB * CHUNKS)           // 1024 blocks; 4 waves = 4 horizontal stripes

// partials layout: ws[bid*8 + k], k = {Sp0, SLp0, Sp1, SLp1, N, NL, 0, 0}
__global__ __launch_bounds__(256, 4) void ul_main(const float* __restrict__ pred,
                                                  const float* __restrict__ target,
                                                  float* __restrict__ partials) {
    const int wv   = threadIdx.x >> 6;     // stripe 0..3
    const int lane = threadIdx.x & 63;
    const int b     = blockIdx.x >> 7;     // batch
    const int chunk = blockIdx.x & 127;
    const int r0    = chunk * ROWS;
    const int col4  = wv * 256 + lane * 4;

    const float* __restrict__ t1p = target + (size_t)(2 * b + 1) * (HH * WW);
    const float* __restrict__ p0p = pred   + (size_t)(2 * b)     * (HH * WW);
    const float* __restrict__ p1p = p0p + (size_t)(HH * WW);

    // ---- phase 1: ALL label loads (10 independent float4, nothing else) ----
    float4 vm[ROWS + 2];
    #pragma unroll
    for (int i = 0; i < ROWS + 2; ++i) {
        int h = r0 - 1 + i;
        h = h < 0 ? 0 : (h >= HH ? HH - 1 : h);
        vm[i] = *(const float4*)(t1p + (size_t)h * WW + col4);
    }

    // ---- phase 2: pack nibbles + neighbor bits (all in registers) ----
    unsigned long long ppack = 0;
    unsigned plpack = 0, prpack = 0, myL = 0, myR = 0;
    #pragma unroll
    for (int i = 0; i < ROWS + 2; ++i) {
        const unsigned p = (vm[i].x > 0.5f ? 1u : 0u) | (vm[i].y > 0.5f ? 2u : 0u) |
                           (vm[i].z > 0.5f ? 4u : 0u) | (vm[i].w > 0.5f ? 8u : 0u);
        ppack |= (unsigned long long)p << (4 * i);
        myL   |= (p & 1u) << i;
        myR   |= ((p >> 3) & 1u) << i;
        plpack |= (((__shfl_up(p, 1) >> 3) & 1u)) << i;
        prpack |= ((__shfl_down(p, 1) & 1u)) << i;
    }

    // ---- in-block halo exchange: all 4 stripes of this row band are here ----
    __shared__ unsigned eL[4], eR[4];
    const unsigned lbm = __shfl(myL, 0);    // this wave's left edge column bits
    const unsigned rbm = __shfl(myR, 63);   // this wave's right edge column bits
    if (lane == 0) { eL[wv] = lbm; eR[wv] = rbm; }
    __syncthreads();
    const unsigned Lh = (wv > 0) ? eR[wv - 1] : lbm;   // clamp at image edge = own col
    const unsigned Rh = (wv < 3) ? eL[wv + 1] : rbm;

    // ---- phase 3a: 6-bit windows -> per-row uniformity nibbles ----
    unsigned w6[ROWS + 2];
    #pragma unroll
    for (int i = 0; i < ROWS + 2; ++i) {
        const unsigned p  = (unsigned)(ppack >> (4 * i)) & 0xFu;
        const unsigned lb = (lane == 0)  ? ((Lh >> i) & 1u) : ((plpack >> i) & 1u);
        const unsigned rb = (lane == 63) ? ((Rh >> i) & 1u) : ((prpack >> i) & 1u);
        w6[i] = lb | (p << 1) | (rb << 5);
    }
    unsigned unis = 0;
    #pragma unroll
    for (int j = 0; j < ROWS; ++j) {
        const unsigned A = w6[j] & w6[j + 1] & w6[j + 2];
        const unsigned O = w6[j] | w6[j + 1] | w6[j + 2];
        const unsigned u4 = ((A & (A >> 1) & (A >> 2)) | ~(O | (O >> 1) | (O >> 2))) & 0xFu;
        unis |= u4 << (4 * j);
    }

    // ---- phase 3b: gather — branch bodies contain ONLY loads ----
    float4 x0[ROWS], x1[ROWS];
    #pragma unroll
    for (int j = 0; j < ROWS; ++j) {
        if ((unis >> (4 * j)) & 0xFu) {
            const size_t off = (size_t)(r0 + j) * WW + col4;
            x0[j] = *(const float4*)(p0p + off);
            x1[j] = *(const float4*)(p1p + off);
        }
    }

    // ---- phase 3c: consume ----
    float s_p0 = 0.f, s_lp0 = 0.f, s_p1 = 0.f, s_lp1 = 0.f;
    int nC = 0, nL = 0;
    #pragma unroll
    for (int j = 0; j < ROWS; ++j) {
        const unsigned uni = (unis >> (4 * j)) & 0xFu;
        if (uni) {
            const unsigned lb4 = (unsigned)(ppack >> (4 * (j + 1))) & 0xFu;
            nC += __popc(uni);
            nL += __popc(uni & lb4);
            #define UL_DO_K(K, C0, C1)                                          \
                if ((uni >> K) & 1u) {                                          \
                    float sg0 = 1.0f / (1.0f + expf(-(C0)));                    \
                    float sg1 = 1.0f / (1.0f + expf(-(C1)));                    \
                    sg0 = fminf(fmaxf(sg0, 1e-7f), 1.0f - 1e-7f);               \
                    sg1 = fminf(fmaxf(sg1, 1e-7f), 1.0f - 1e-7f);               \
                    s_p0 += sg0; s_p1 += sg1;                                   \
                    if ((lb4 >> K) & 1u) { s_lp0 += sg0; s_lp1 += sg1; }        \
                }
            UL_DO_K(0, x0[j].x, x1[j].x)
            UL_DO_K(1, x0[j].y, x1[j].y)
            UL_DO_K(2, x0[j].z, x1[j].z)
            UL_DO_K(3, x0[j].w, x1[j].w)
            #undef UL_DO_K
        }
    }

    // ---- wave reduce (4 floats + 2 ints) ----
    #pragma unroll
    for (int off = 32; off; off >>= 1) {
        s_p0  += __shfl_xor(s_p0,  off, 64);
        s_lp0 += __shfl_xor(s_lp0, off, 64);
        s_p1  += __shfl_xor(s_p1,  off, 64);
        s_lp1 += __shfl_xor(s_lp1, off, 64);
        nC    += __shfl_xor(nC,    off, 64);
        nL    += __shfl_xor(nL,    off, 64);
    }

    __shared__ float sm[4][6];
    if (lane == 0) {
        sm[wv][0] = s_p0;  sm[wv][1] = s_lp0;
        sm[wv][2] = s_p1;  sm[wv][3] = s_lp1;
        sm[wv][4] = (float)nC; sm[wv][5] = (float)nL;
    }
    __syncthreads();
    if (threadIdx.x < 8) {
        const int k = threadIdx.x;
        const float v = (k < 6) ? (sm[0][k] + sm[1][k] + sm[2][k] + sm[3][k]) : 0.0f;
        partials[(size_t)blockIdx.x * 8 + k] = v;
    }
}

// Stage 2: reduce 1024 x 8 partials (float4, parity classes), compute scalar loss
__global__ __launch_bounds__(256) void ul_final(const float* __restrict__ ws,
                                                float* __restrict__ out) {
    const int t = threadIdx.x, lane = t & 63, wv = t >> 6;
    float a0 = 0.f, a1 = 0.f, a2 = 0.f, a3 = 0.f;
    #pragma unroll
    for (int r = 0; r < 8; ++r) {                 // 2048 float4s total
        const float4 v = ((const float4*)ws)[t + 256 * r];
        a0 += v.x; a1 += v.y; a2 += v.z; a3 += v.w;
    }
    // butterfly keeping parity class (even t = {Sp0,SLp0,Sp1,SLp1}, odd t = {N,NL,0,0})
    #pragma unroll
    for (int off = 32; off >= 2; off >>= 1) {
        a0 += __shfl_xor(a0, off, 64); a1 += __shfl_xor(a1, off, 64);
        a2 += __shfl_xor(a2, off, 64); a3 += __shfl_xor(a3, off, 64);
    }
    __shared__ float sm[4][2][4];
    if (lane < 2) {
        sm[wv][lane][0] = a0; sm[wv][lane][1] = a1;
        sm[wv][lane][2] = a2; sm[wv][lane][3] = a3;
    }
    __syncthreads();
    if (t == 0) {
        float Sp0 = 0.f, SLp0 = 0.f, Sp1 = 0.f, SLp1 = 0.f, N = 0.f, NL = 0.f;
        #pragma unroll
        for (int w = 0; w < 4; ++w) {
            Sp0 += sm[w][0][0]; SLp0 += sm[w][0][1];
            Sp1 += sm[w][0][2]; SLp1 += sm[w][0][3];
            N   += sm[w][1][0]; NL   += sm[w][1][1];
        }
        const float tp0 = 0.95f * Sp0 - 0.9f * SLp0;
        const float st0 = 0.95f * N   - 0.9f * NL;
        const float fn0 = st0 - tp0;
        const float fp0 = Sp0 - tp0;
        const float tp1 = 0.05f * Sp1 + 0.9f * SLp1;
        const float st1 = 0.05f * N   + 0.9f * NL;
        const float fn1 = st1 - tp1;
        const float fp1 = Sp1 - tp1;
        const float d0 = (tp0 + 1e-7f) / (tp0 + 0.6f * fn0 + 0.4f * fp0 + 1e-7f);
        const float d1 = (tp1 + 1e-7f) / (tp1 + 0.6f * fn1 + 0.4f * fp1 + 1e-7f);
        const float back = 1.0f - d0;
        const float fore = sqrtf(fmaxf(1.0f - d1, 0.0f));   // (1-d)*(1-d)^-0.5
        out[0] = 0.5f * (back + fore);                       // WEIGHT=1 kills CE term
    }
}

extern "C" void kernel_launch(void* const* d_in, const int* in_sizes, int n_in,
                              void* d_out, int out_size, void* d_ws, size_t ws_size,
                              hipStream_t stream) {
    const float* pred   = (const float*)d_in[0];
    const float* target = (const float*)d_in[1];
    float* partials = (float*)d_ws;    // 1024 * 8 floats = 32 KiB
    float* out      = (float*)d_out;

    ul_main<<<NBLK, 256, 0, stream>>>(pred, target, partials);
    ul_final<<<1, 256, 0, stream>>>(partials, out);
}